// Round 1
// baseline (176.195 us; speedup 1.0000x reference)
//
#include <hip/hip_runtime.h>
#include <math.h>

#define BB 32
#define LL 256
#define DD 16
#define HH 64
#define KK 5
#define TT 252          // LL - KK + 1
#define PP 126          // TT/2
#define SS 8064         // HH*PP
#define NCHUNK 32
#define CHUNK 252       // SS / NCHUNK
#define TCOL 128        // columns per block in matmul

// ---------------- kernel 1: conv + relu + pair-pool (+ mainT transpose) ----
__global__ __launch_bounds__(256) void k1_conv(
    const float* __restrict__ x, const float* __restrict__ cw,
    const float* __restrict__ cb, float* __restrict__ y,
    float* __restrict__ flat, float* __restrict__ mainT) {
  int idx = blockIdx.x * 256 + threadIdx.x;   // total = B*D*H*P = 4,128,768
  int p = idx % PP;
  int t1 = idx / PP;
  int h = t1 % HH;
  t1 /= HH;
  int d = t1 % DD;
  int b = t1 / DD;

  const float* xp = x + ((size_t)(b * LL + 2 * p)) * DD + d; // x[b, 2p+k, d] = xp[k*DD]
  const float* wp = cw + (size_t)(d * HH + h) * KK;
  float w0 = wp[0], w1 = wp[1], w2 = wp[2], w3 = wp[3], w4 = wp[4];
  float bias = cb[d * HH + h];

  float x0 = xp[0], x1 = xp[DD], x2 = xp[2 * DD], x3 = xp[3 * DD],
        x4 = xp[4 * DD], x5 = xp[5 * DD];

  float y0 = fmaf(w4, x4, fmaf(w3, x3, fmaf(w2, x2, fmaf(w1, x1, fmaf(w0, x0, bias)))));
  float y1 = fmaf(w4, x5, fmaf(w3, x4, fmaf(w2, x3, fmaf(w1, x2, fmaf(w0, x1, bias)))));
  y0 = fmaxf(y0, 0.f);
  y1 = fmaxf(y1, 0.f);

  int row = (b * DD + d) * HH + h;            // channel row into y
  reinterpret_cast<float2*>(y + (size_t)row * TT)[p] = make_float2(y0, y1);

  float pooled = 0.5f * (y0 + y1);
  flat[(size_t)(b * DD + d) * SS + h * PP + p] = pooled;
  if (d == 0) mainT[(size_t)(h * PP + p) * BB + b] = pooled;
}

// ---------------- kernel 2: transposed-conv recon ---------------------------
__global__ __launch_bounds__(256) void k2_recon(
    const float* __restrict__ y, const float* __restrict__ dw,
    const float* __restrict__ db, float* __restrict__ recon) {
  int bd = blockIdx.x;            // b*DD + d
  int b = bd / DD, d = bd % DD;
  __shared__ float ylds[HH * TT];  // 64*252*4 = 64512 B
  const float* yrow = y + (size_t)(b * DD + d) * HH * TT;
  for (int off = threadIdx.x; off < HH * TT; off += 256) ylds[off] = yrow[off];
  __syncthreads();

  int l = threadIdx.x;            // 0..255 output position
  float acc = db[d];
  for (int h = 0; h < HH; ++h) {
    const float* w = dw + (size_t)(d * HH + h) * KK;
    const float* yl = ylds + h * TT;
    #pragma unroll
    for (int j = 0; j < KK; ++j) {
      int t = l - j;
      if (t >= 0 && t < TT) acc = fmaf(yl[t], w[j], acc);
    }
  }
  recon[(size_t)bd * LL + l] = acc;
}

// ---------------- kernel 3: m-partial = main @ W_attn (chunked over s) ------
__global__ __launch_bounds__(TCOL) void k3_matmul(
    const float* __restrict__ W, const float* __restrict__ mainT,
    float* __restrict__ partial) {
  int col = blockIdx.x * TCOL + threadIdx.x;   // 0..8063
  int chunk = blockIdx.y;                      // 0..31
  int s0 = chunk * CHUNK;

  float acc[BB];
  #pragma unroll
  for (int b = 0; b < BB; ++b) acc[b] = 0.f;

  const float* wp = W + (size_t)s0 * SS + col;
  const float* mp = mainT + (size_t)s0 * BB;

  #pragma unroll 4
  for (int s = 0; s < CHUNK; ++s) {
    float w = wp[(size_t)s * SS];
    #pragma unroll
    for (int b = 0; b < BB; ++b)
      acc[b] = fmaf(mp[s * BB + b], w, acc[b]);
  }

  float* pp = partial + (size_t)chunk * (BB * SS) + col;
  #pragma unroll
  for (int b = 0; b < BB; ++b) pp[(size_t)b * SS] = acc[b];
}

// ---------------- kernel 3b: reduce partials -> m ---------------------------
__global__ __launch_bounds__(256) void k3b_reduce(
    const float* __restrict__ partial, float* __restrict__ m) {
  int i = blockIdx.x * 256 + threadIdx.x;      // < BB*SS = 258048
  float s = 0.f;
  #pragma unroll
  for (int c = 0; c < NCHUNK; ++c) s += partial[(size_t)c * (BB * SS) + i];
  m[i] = s;
}

// ---------------- kernel 4: scores[b,d'] = <m[b,:], aux[b,d',:]> ------------
__global__ __launch_bounds__(256) void k4_scores(
    const float* __restrict__ m, const float* __restrict__ flat,
    float* __restrict__ scores) {
  int bd = blockIdx.x;            // b*15 + dd
  int b = bd / 15, dd = bd % 15;
  const float* mb = m + (size_t)b * SS;
  const float* ab = flat + ((size_t)b * DD + 1 + dd) * SS;
  float p = 0.f;
  for (int s = threadIdx.x; s < SS; s += 256) p = fmaf(mb[s], ab[s], p);
  #pragma unroll
  for (int o = 32; o; o >>= 1) p += __shfl_xor(p, o);
  __shared__ float red[4];
  if ((threadIdx.x & 63) == 0) red[threadIdx.x >> 6] = p;
  __syncthreads();
  if (threadIdx.x == 0) scores[bd] = red[0] + red[1] + red[2] + red[3];
}

// ---------------- kernel 5: softmax over 15 ---------------------------------
__global__ __launch_bounds__(64) void k5_softmax(
    const float* __restrict__ scores, float* __restrict__ attn_out) {
  int b = blockIdx.x;
  int lane = threadIdx.x;
  float v = (lane < 15) ? scores[b * 15 + lane] : -INFINITY;
  float mx = v;
  #pragma unroll
  for (int o = 32; o; o >>= 1) mx = fmaxf(mx, __shfl_xor(mx, o));
  float e = (lane < 15) ? expf(v - mx) : 0.f;
  float sum = e;
  #pragma unroll
  for (int o = 32; o; o >>= 1) sum += __shfl_xor(sum, o);
  if (lane < 15) attn_out[b * 15 + lane] = e / sum;
}

// ---------------- kernel 6: main copy + weighted sum ------------------------
__global__ __launch_bounds__(256) void k6_out(
    const float* __restrict__ flat, const float* __restrict__ attn,
    float* __restrict__ out) {
  int b = blockIdx.y;
  int s = blockIdx.x * 256 + threadIdx.x;
  if (s >= SS) return;
  const float* fb = flat + (size_t)b * DD * SS;
  out[(size_t)b * 2 * SS + s] = fb[s];
  float w = 0.f;
  #pragma unroll
  for (int d = 0; d < 15; ++d)
    w = fmaf(attn[b * 15 + d], fb[(size_t)(1 + d) * SS + s], w);
  out[(size_t)b * 2 * SS + SS + s] = w;
}

// ---------------------------------------------------------------------------
extern "C" void kernel_launch(void* const* d_in, const int* in_sizes, int n_in,
                              void* d_out, int out_size, void* d_ws, size_t ws_size,
                              hipStream_t stream) {
  const float* x        = (const float*)d_in[0];
  const float* conv_w   = (const float*)d_in[1];
  const float* conv_b   = (const float*)d_in[2];
  const float* deconv_w = (const float*)d_in[3];
  const float* deconv_b = (const float*)d_in[4];
  const float* W_attn   = (const float*)d_in[5];
  float* out = (float*)d_out;

  // output layout: [ out (B*2S = 516096) | attn (B*15 = 480) | recon (B*D*L = 131072) ]
  const size_t ATTN_OFF  = (size_t)BB * 2 * SS;       // 516096
  const size_t RECON_OFF = ATTN_OFF + (size_t)BB * 15; // 516576

  // workspace layout (floats); partial aliases y (y dead after k2; same size 8,257,536)
  float* ws     = (float*)d_ws;
  float* y      = ws;                                  // 8,257,536 floats
  float* partial= ws;                                  // NCHUNK*BB*SS = 8,257,536 floats
  float* flat   = ws + (size_t)BB * DD * HH * TT;      // + 8,257,536 -> 4,128,768 floats
  float* mainT  = flat + (size_t)BB * DD * SS;         // + 4,128,768 -> 258,048 floats
  float* m      = mainT + (size_t)SS * BB;             // + 258,048   -> 258,048 floats
  float* scores = m + (size_t)BB * SS;                 // + 258,048   -> 480 floats

  // 1) conv + relu + pool
  k1_conv<<<dim3((BB * DD * HH * PP) / 256), dim3(256), 0, stream>>>(
      x, conv_w, conv_b, y, flat, mainT);

  // 2) recon (reads y; y dead afterwards)
  k2_recon<<<dim3(BB * DD), dim3(256), 0, stream>>>(
      y, deconv_w, deconv_b, out + RECON_OFF);

  // 3) big matmul partials (overwrites y region)
  k3_matmul<<<dim3(SS / TCOL, NCHUNK), dim3(TCOL), 0, stream>>>(
      W_attn, mainT, partial);

  // 3b) reduce -> m
  k3b_reduce<<<dim3((BB * SS) / 256), dim3(256), 0, stream>>>(partial, m);

  // 4) scores
  k4_scores<<<dim3(BB * 15), dim3(256), 0, stream>>>(m, flat, scores);

  // 5) softmax -> attn section of out
  k5_softmax<<<dim3(BB), dim3(64), 0, stream>>>(scores, out + ATTN_OFF);

  // 6) main copy + weighted
  k6_out<<<dim3((SS + 255) / 256, BB), dim3(256), 0, stream>>>(
      flat, out + ATTN_OFF, out);
}